// Round 11
// baseline (4049.483 us; speedup 1.0000x reference)
//
#include <hip/hip_runtime.h>

// Soft product quantizer — two-kernel f16-dot2 pipeline.
// z:(8,384,32,32) f32, C:(2048,384) f32. 4096 pairs (n, n+4096) x K=8, d=48, M=2048.
// s = 2<x,c> - |c|^2 (x^2 cancels; |s| small -> no max-subtract).
// K1 (stats): Z = sum e^s, T = sum e^s*s per row -> ws[(k<<13)+n] = (1/Z, ent).
// K2 (out):   recompute s, O = sum e^s*c (packed-f16 pk_fma), cross-JSD, store.
// Lanes: pr=lane&7 (pair), cs=lane>>3 (codes m ≡ cs mod 8). Each lane handles
// BOTH rows of its pair (one LDS code-read serves p and q). Block = 4 waves =
// 32 pairs, one k; grid 128x8 = 1024. C tile (64 codes f16, stride 56 u16 =
// 112B) double-buffered; 8 distinct read rows/instr hit distinct 16B slots
// (112*cs mod 128) -> conflict-free.

typedef __fp16 f16;
typedef __attribute__((ext_vector_type(2))) __fp16 f16x2;

#define Z_BCH   (384*1024)
#define JSD_IDX 3145728

__device__ __forceinline__ f16x2 u2h(unsigned u) {
    union { unsigned u; f16x2 h; } c; c.u = u; return c.h;
}
__device__ __forceinline__ unsigned h2u(f16x2 h) {
    union { f16x2 h; unsigned u; } c; c.h = h; return c.u;
}
__device__ __forceinline__ float fdot2f(f16x2 a, f16x2 b, float c) {
#if __has_builtin(__builtin_amdgcn_fdot2)
    return __builtin_amdgcn_fdot2(a, b, c, false);
#else
    return fmaf((float)a.y, (float)b.y, fmaf((float)a.x, (float)b.x, c));
#endif
}

// ---- shared structure macros (both kernels declare the same locals) ----
#define PQ_PROLOG                                                             \
    const int tid  = threadIdx.x;                                             \
    const int lane = tid & 63;                                                \
    const int wv   = tid >> 6;                                                \
    const int pr   = lane & 7;                                                \
    const int cs   = lane >> 3;          /* 0..7 */                           \
    const int pg   = blockIdx.x & 127;                                        \
    const int k    = blockIdx.x >> 7;                                         \
    const int pairIdx = pg*32 + wv*8 + pr;                                    \
    const size_t basep = (size_t)(pairIdx >> 10)*Z_BCH + (pairIdx & 1023);    \
    const int nq = pairIdx + 4096;                                            \
    const size_t baseq = (size_t)(nq >> 10)*Z_BCH + (nq & 1023);              \
    f16x2 xp[26], xq[26];                                                     \
    _Pragma("unroll")                                                         \
    for (int j = 0; j < 24; ++j) {                                            \
        xp[j] = __builtin_amdgcn_cvt_pkrtz(                                   \
            2.f*Zin[basep + (size_t)(k*48 + 2*j)*1024],                       \
            2.f*Zin[basep + (size_t)(k*48 + 2*j + 1)*1024]);                  \
        xq[j] = __builtin_amdgcn_cvt_pkrtz(                                   \
            2.f*Zin[baseq + (size_t)(k*48 + 2*j)*1024],                       \
            2.f*Zin[baseq + (size_t)(k*48 + 2*j + 1)*1024]);                  \
    }                                                                         \
    xp[24] = __builtin_amdgcn_cvt_pkrtz(-1.f, -1.f);                          \
    xp[25] = xp[24]; xq[24] = xp[24]; xq[25] = xp[24];                        \
    const int sm = tid & 63, p8 = tid >> 6;                                   \
    unsigned w0, w1, w2, w3, w4, w5; unsigned short wc2;

#define SLOAD(m0) do {                                                        \
        const float* _p = Cb + (size_t)((m0) + sm)*384 + k*48 + p8*12;        \
        float4 va = *(const float4*)(_p);                                     \
        float4 vb = *(const float4*)(_p + 4);                                 \
        float4 vc = *(const float4*)(_p + 8);                                 \
        w0 = h2u(__builtin_amdgcn_cvt_pkrtz(va.x, va.y));                     \
        w1 = h2u(__builtin_amdgcn_cvt_pkrtz(va.z, va.w));                     \
        w2 = h2u(__builtin_amdgcn_cvt_pkrtz(vb.x, vb.y));                     \
        w3 = h2u(__builtin_amdgcn_cvt_pkrtz(vb.z, vb.w));                     \
        w4 = h2u(__builtin_amdgcn_cvt_pkrtz(vc.x, vc.y));                     \
        w5 = h2u(__builtin_amdgcn_cvt_pkrtz(vc.z, vc.w));                     \
        float c2 = va.x*va.x + va.y*va.y + va.z*va.z + va.w*va.w              \
                 + vb.x*vb.x + vb.y*vb.y + vb.z*vb.z + vb.w*vb.w              \
                 + vc.x*vc.x + vc.y*vc.y + vc.z*vc.z + vc.w*vc.w;             \
        wc2 = (unsigned short)(h2u(__builtin_amdgcn_cvt_pkrtz(c2, 0.f)) & 0xFFFF); \
    } while (0)

#define SWRITE(b) do {                                                        \
        *(uint2*)&cbuf[b][sm][p8*12    ] = make_uint2(w0, w1);                \
        *(uint2*)&cbuf[b][sm][p8*12 + 4] = make_uint2(w2, w3);                \
        *(uint2*)&cbuf[b][sm][p8*12 + 8] = make_uint2(w4, w5);                \
        cbuf[b][sm][48 + p8] = wc2;                                           \
    } while (0)

#define LOADCW(b, m)                                                          \
    unsigned cw[24]; uint2 c2w;                                               \
    {   uint4 q0 = *(const uint4*)&cbuf[b][m][0];                             \
        uint4 q1 = *(const uint4*)&cbuf[b][m][8];                             \
        uint4 q2 = *(const uint4*)&cbuf[b][m][16];                            \
        uint4 q3 = *(const uint4*)&cbuf[b][m][24];                            \
        uint4 q4 = *(const uint4*)&cbuf[b][m][32];                            \
        uint4 q5 = *(const uint4*)&cbuf[b][m][40];                            \
        cw[0]=q0.x;  cw[1]=q0.y;  cw[2]=q0.z;  cw[3]=q0.w;                    \
        cw[4]=q1.x;  cw[5]=q1.y;  cw[6]=q1.z;  cw[7]=q1.w;                    \
        cw[8]=q2.x;  cw[9]=q2.y;  cw[10]=q2.z; cw[11]=q2.w;                   \
        cw[12]=q3.x; cw[13]=q3.y; cw[14]=q3.z; cw[15]=q3.w;                   \
        cw[16]=q4.x; cw[17]=q4.y; cw[18]=q4.z; cw[19]=q4.w;                   \
        cw[20]=q5.x; cw[21]=q5.y; cw[22]=q5.z; cw[23]=q5.w;                   \
        c2w = *(const uint2*)&cbuf[b][m][48];                                 \
    }

__device__ __forceinline__ float dot48(const unsigned* cw, uint2 c2w, const f16x2* xv) {
    float sA = 0.f, sB = 0.f;
#pragma unroll
    for (int j = 0; j < 24; j += 2) {
        sA = fdot2f(u2h(cw[j]),   xv[j],   sA);
        sB = fdot2f(u2h(cw[j+1]), xv[j+1], sB);
    }
    sA = fdot2f(u2h(c2w.x), xv[24], sA);
    sB = fdot2f(u2h(c2w.y), xv[25], sB);
    return sA + sB;
}

// =========================== kernel 1: stats ===========================
__global__ __launch_bounds__(256, 4)
void pq_stats(const float* __restrict__ Zin, const float* __restrict__ Cb,
              float2* __restrict__ Ws)
{
    __shared__ __align__(16) unsigned short cbuf[2][64][56];
    PQ_PROLOG

    float Zp = 0.f, Tp = 0.f, Zq = 0.f, Tq = 0.f;
    SLOAD(0); SWRITE(0);
    __syncthreads();
    int buf = 0;
#pragma unroll 1
    for (int t = 0; t < 32; ++t) {
        if (t < 31) SLOAD((t + 1)*64);
#pragma unroll
        for (int mb = 0; mb < 8; ++mb) {
            const int m = mb*8 + cs;
            LOADCW(buf, m);
            float sp = dot48(cw, c2w, xp);
            float sq = dot48(cw, c2w, xq);
            float e1 = __expf(sp), e2 = __expf(sq);
            Zp += e1; Tp = fmaf(e1, sp, Tp);
            Zq += e2; Tq = fmaf(e2, sq, Tq);
        }
        if (t < 31) SWRITE(buf ^ 1);
        __syncthreads();
        buf ^= 1;
    }
    // reduce over the 8 code-classes (lane bits 3..5)
#pragma unroll
    for (int off = 8; off < 64; off <<= 1) {
        Zp += __shfl_xor(Zp, off); Tp += __shfl_xor(Tp, off);
        Zq += __shfl_xor(Zq, off); Tq += __shfl_xor(Tq, off);
    }
    if (cs == 0) {
        float i1 = 1.f/Zp, i2 = 1.f/Zq;
        Ws[(k << 13) + pairIdx] = make_float2(i1, Tp*i1 - __logf(Zp));
        Ws[(k << 13) + nq]      = make_float2(i2, Tq*i2 - __logf(Zq));
    }
}

// =========================== kernel 2: output ===========================
__global__ __launch_bounds__(256, 3)
void pq_out(const float* __restrict__ Zin, const float* __restrict__ Cb,
            const float2* __restrict__ Ws, float* __restrict__ Out)
{
    __shared__ __align__(16) unsigned short cbuf[2][64][56];
    __shared__ float jred[4];
    PQ_PROLOG

    const float2 wp = Ws[(k << 13) + pairIdx];
    const float2 wq = Ws[(k << 13) + nq];
    const float izp = wp.x, izq = wq.x;

    f16x2 Op[24], Oq[24];
#pragma unroll
    for (int j = 0; j < 24; ++j) { Op[j] = u2h(0u); Oq[j] = u2h(0u); }
    float cross = 0.f;

    SLOAD(0); SWRITE(0);
    __syncthreads();
    int buf = 0;
#pragma unroll 1
    for (int t = 0; t < 32; ++t) {
        if (t < 31) SLOAD((t + 1)*64);
#pragma unroll
        for (int mb = 0; mb < 8; ++mb) {
            const int m = mb*8 + cs;
            LOADCW(buf, m);
            float sp = dot48(cw, c2w, xp);
            float sq = dot48(cw, c2w, xq);
            float e1 = __expf(sp), e2 = __expf(sq);
            float ssum = fmaf(e1, izp, e2*izq);           // p + q
            cross = fmaf(ssum, __logf(fmaf(0.5f, ssum, 1e-12f)), cross);
            f16x2 ep = __builtin_amdgcn_cvt_pkrtz(e1, e1);
            f16x2 eq = __builtin_amdgcn_cvt_pkrtz(e2, e2);
#pragma unroll
            for (int j = 0; j < 24; ++j) {                // v_pk_fma_f16
                Op[j] = u2h(cw[j])*ep + Op[j];
                Oq[j] = u2h(cw[j])*eq + Oq[j];
            }
        }
        if (t < 31) SWRITE(buf ^ 1);
        __syncthreads();
        buf ^= 1;
    }

    // ---- JSD: cross covers this lane's m-class only; ent once per pair ----
    float jloc = ((cs == 0) ? (wp.y + wq.y) : 0.f) - cross;
#pragma unroll
    for (int off = 1; off < 64; off <<= 1) jloc += __shfl_xor(jloc, off);
    if (lane == 0) jred[wv] = jloc;
    __syncthreads();
    if (tid == 0)
        atomicAdd(Out + JSD_IDX,
                  (jred[0] + jred[1] + jred[2] + jred[3]) * (0.5f / 32768.f));

    // ---- reduce O over code-classes (packed f16 adds) ----
#pragma unroll
    for (int off = 8; off < 64; off <<= 1)
#pragma unroll
        for (int j = 0; j < 24; ++j) {
            Op[j] = Op[j] + u2h(__shfl_xor(h2u(Op[j]), off));
            Oq[j] = Oq[j] + u2h(__shfl_xor(h2u(Oq[j]), off));
        }

    // ---- store: lane cs stores dims [cs*6, cs*6+6) of both rows ----
#pragma unroll
    for (int r = 0; r < 3; ++r) {
        const int j = 3*cs + r;                // f16x2 reg covers dims 2j, 2j+1
        f16x2 vp = Op[j], vq = Oq[j];
        const int ch = k*48 + 2*j;
        Out[basep + (size_t)(ch    )*1024] = (float)vp.x * izp;
        Out[basep + (size_t)(ch + 1)*1024] = (float)vp.y * izp;
        Out[baseq + (size_t)(ch    )*1024] = (float)vq.x * izq;
        Out[baseq + (size_t)(ch + 1)*1024] = (float)vq.y * izq;
    }
}

extern "C" void kernel_launch(void* const* d_in, const int* in_sizes, int n_in,
                              void* d_out, int out_size, void* d_ws, size_t ws_size,
                              hipStream_t stream)
{
    const float* z = (const float*)d_in[0];
    const float* C = (const float*)d_in[1];
    float* out = (float*)d_out;
    float2* ws = (float2*)d_ws;   // 8 k * 8192 rows * (1/Z, ent) = 512 KB

    hipMemsetAsync(out + JSD_IDX, 0, sizeof(float), stream);

    pq_stats<<<dim3(1024), dim3(256), 0, stream>>>(z, C, ws);
    pq_out  <<<dim3(1024), dim3(256), 0, stream>>>(z, C, ws, out);
}